// Round 1
// baseline (290.731 us; speedup 1.0000x reference)
//
#include <hip/hip_runtime.h>
#include <hip/hip_bf16.h>
#include <stdint.h>

#define BB 2
#define SS 2048
#define DMM 2048
#define HH 16
#define DHH 128

typedef unsigned short u16;
typedef __attribute__((ext_vector_type(8))) short bf16x8;
typedef __attribute__((ext_vector_type(8))) unsigned short u16x8;
typedef __attribute__((ext_vector_type(4))) float f32x4;

__device__ __forceinline__ u16 f2bf(float f) {
  union { float f; uint32_t u; } v; v.f = f;
  return (u16)((v.u + 0x7FFFu + ((v.u >> 16) & 1u)) >> 16);  // RNE
}

__device__ __forceinline__ void stage16(const void* g, void* l) {
  __builtin_amdgcn_global_load_lds(
      (const __attribute__((address_space(1))) void*)g,
      (__attribute__((address_space(3))) void*)l, 16, 0, 0);
}

// ---------------- f32 -> bf16 convert, 8 elems/thread ----------------
__global__ void cvt_bf16_k(const float* __restrict__ in, u16* __restrict__ out) {
  size_t i = (size_t)blockIdx.x * blockDim.x + threadIdx.x;
  const float4* p = (const float4*)in + i * 2;
  float4 a = p[0], b = p[1];
  u16x8 v;
  v[0] = f2bf(a.x); v[1] = f2bf(a.y); v[2] = f2bf(a.z); v[3] = f2bf(a.w);
  v[4] = f2bf(b.x); v[5] = f2bf(b.y); v[6] = f2bf(b.z); v[7] = f2bf(b.w);
  *((u16x8*)out + i) = v;
}

// ---------------- 128x128-tile GEMM, C = A[M][K] * B[N][K]^T ----------------
// MODE 0: epilogue = +bias, per-head rope (fc indexed by HEAD per reference),
//         scatter to Q (scaled), K as [bh][s][128], V transposed [bh][128][s]
// MODE 1: epilogue = +bias, f32 row-major out
template<int MODE>
__global__ __launch_bounds__(256)
void gemm_bt_k(const u16* __restrict__ A, const u16* __restrict__ Bm,
               const float* __restrict__ bias,
               const float* __restrict__ fcr, const float* __restrict__ fci,
               u16* __restrict__ Qo, u16* __restrict__ Ko, u16* __restrict__ Vto,
               float* __restrict__ Fo,
               int Mdim, int Ndim, int Kdim)
{
  const int tid = threadIdx.x;
  const int lane = tid & 63, w = tid >> 6, g = lane >> 4, c = lane & 15;
  const int bn = blockIdx.x, bm = blockIdx.y;

  __shared__ __align__(16) u16 As[128 * 64];
  __shared__ __align__(16) u16 Bs[128 * 64];

  constexpr int MF = (MODE == 0) ? 2 : 4;
  constexpr int NF = (MODE == 0) ? 8 : 4;
  const int wrow = (MODE == 0) ? w * 32 : (w >> 1) * 64;
  const int wcol = (MODE == 0) ? 0 : (w & 1) * 64;

  f32x4 acc[MF][NF] = {};

  const char* Abase = (const char*)A + ((long)bm * 128) * Kdim * 2;
  const char* Bbase = (const char*)Bm + ((long)bn * 128) * Kdim * 2;
  const int wub = w * 1024;

  for (int kb = 0; kb < Kdim; kb += 64) {
    // stage A tile [128 rows][64 k] (rows = 128B) with inverse-swizzled source
    #pragma unroll
    for (int i = 0; i < 4; ++i) {
      int ob = i * 4096 + wub;
      int o = ob + (lane << 4);
      int r = o >> 7, cb = o & 127;
      int cbs = cb ^ ((r & 7) << 4);
      stage16(Abase + ((long)r * Kdim + kb) * 2 + cbs, (char*)As + ob);
    }
    #pragma unroll
    for (int i = 0; i < 4; ++i) {
      int ob = i * 4096 + wub;
      int o = ob + (lane << 4);
      int r = o >> 7, cb = o & 127;
      int cbs = cb ^ ((r & 7) << 4);
      stage16(Bbase + ((long)r * Kdim + kb) * 2 + cbs, (char*)Bs + ob);
    }
    __syncthreads();
    #pragma unroll
    for (int kc = 0; kc < 2; ++kc) {
      bf16x8 af[MF], bfr[NF];
      #pragma unroll
      for (int mf = 0; mf < MF; ++mf) {
        int r = wrow + mf * 16 + c;
        int ab = (r << 7) + kc * 64 + (g << 4);
        ab ^= (r & 7) << 4;
        af[mf] = *(const bf16x8*)((const char*)As + ab);
      }
      #pragma unroll
      for (int nf = 0; nf < NF; ++nf) {
        int r = wcol + nf * 16 + c;
        int ab = (r << 7) + kc * 64 + (g << 4);
        ab ^= (r & 7) << 4;
        bfr[nf] = *(const bf16x8*)((const char*)Bs + ab);
      }
      #pragma unroll
      for (int mf = 0; mf < MF; ++mf)
        #pragma unroll
        for (int nf = 0; nf < NF; ++nf)
          acc[mf][nf] = __builtin_amdgcn_mfma_f32_16x16x32_bf16(af[mf], bfr[nf], acc[mf][nf], 0, 0, 0);
    }
    __syncthreads();
  }

  if constexpr (MODE == 1) {
    #pragma unroll
    for (int mf = 0; mf < MF; ++mf)
      #pragma unroll
      for (int nf = 0; nf < NF; ++nf) {
        int col = bn * 128 + wcol + nf * 16 + c;
        float bv = bias[col];
        #pragma unroll
        for (int j = 0; j < 4; ++j) {
          int row = bm * 128 + wrow + mf * 16 + g * 4 + j;
          Fo[(long)row * Ndim + col] = acc[mf][nf][j] + bv;
        }
      }
  } else {
    const int sec = bn >> 4, h = bn & 15, b = bm >> 4;
    if (sec < 2) {
      // Q or K head tile: rope pairs are frags (nf, nf+4) in the same lane
      const float scale = (sec == 0) ? 0.08838834764831845f : 1.0f;  // DH^-0.5 folded into Q
      u16* O = (sec == 0) ? Qo : Ko;
      #pragma unroll
      for (int nf = 0; nf < 4; ++nf) {
        int d = nf * 16 + c;
        float fr = fcr[h * 64 + d], fi = fci[h * 64 + d];  // per-HEAD angle (ref quirk)
        float bre = bias[bn * 128 + d], bim = bias[bn * 128 + 64 + d];
        #pragma unroll
        for (int mf = 0; mf < MF; ++mf)
          #pragma unroll
          for (int j = 0; j < 4; ++j) {
            int row = bm * 128 + wrow + mf * 16 + g * 4 + j;
            int s = row & (SS - 1);
            float re = acc[mf][nf][j] + bre;
            float im = acc[mf][nf + 4][j] + bim;
            long base = (((long)(b * HH + h)) * SS + s) * DHH;
            O[base + d]      = f2bf((re * fr - im * fi) * scale);
            O[base + 64 + d] = f2bf((re * fi + im * fr) * scale);
          }
      }
    } else {
      // V tile -> transposed layout [bh][d][s]
      #pragma unroll
      for (int nf = 0; nf < 8; ++nf) {
        int d = nf * 16 + c;
        float bv = bias[bn * 128 + d];
        #pragma unroll
        for (int mf = 0; mf < MF; ++mf)
          #pragma unroll
          for (int j = 0; j < 4; ++j) {
            int row = bm * 128 + wrow + mf * 16 + g * 4 + j;
            int s = row & (SS - 1);
            Vto[(((long)(b * HH + h)) * DHH + d) * SS + s] = f2bf(acc[mf][nf][j] + bv);
          }
      }
    }
  }
}

// ---------------- causal flash attention ----------------
// grid: (bh=32, qtiles=32), block 256 = 4 waves x 16 q-rows, KVBLK=64
__global__ __launch_bounds__(256)
void attn_k(const u16* __restrict__ Q, const u16* __restrict__ K,
            const u16* __restrict__ Vt, u16* __restrict__ Ao)
{
  const int tid = threadIdx.x;
  const int lane = tid & 63, w = tid >> 6, g = lane >> 4, c = lane & 15;
  const int bh = blockIdx.x;
  const int qt = (int)(gridDim.y - 1 - blockIdx.y);  // heavy tiles dispatch first
  const int b = bh >> 4, h = bh & 15;
  const int qbase = qt * 64;

  __shared__ __align__(16) u16 Ks[64 * 128];    // rows 256B, XOR-swizzled
  __shared__ __align__(16) u16 Vts[128 * 64];   // [dh][kv], rows 128B, swizzled
  __shared__ __align__(16) u16 Ps[4][16 * 64];  // wave-private P, swizzled

  const long head = (long)bh * SS * DHH;

  bf16x8 qf[4];  // Q rows already scaled by DH^-0.5
  {
    const u16* qp = Q + head + (long)(qbase + w * 16 + c) * DHH + g * 8;
    #pragma unroll
    for (int kc = 0; kc < 4; ++kc) qf[kc] = *(const bf16x8*)(qp + kc * 32);
  }

  f32x4 o[8] = {};
  float m[4], l[4];
  #pragma unroll
  for (int j = 0; j < 4; ++j) { m[j] = -INFINITY; l[j] = 0.f; }

  const int wub = w * 1024;
  for (int t = 0; t <= qt; ++t) {
    const int kvbase = t * 64;
    #pragma unroll
    for (int i = 0; i < 4; ++i) {  // K tile 64x128
      int ob = i * 4096 + wub;
      int o_ = ob + (lane << 4);
      int r = o_ >> 8, cb = o_ & 255;
      int cbs = cb ^ ((r & 7) << 4);
      stage16((const char*)(K + head) + (long)(kvbase + r) * 256 + cbs, (char*)Ks + ob);
    }
    #pragma unroll
    for (int i = 0; i < 4; ++i) {  // Vt tile 128x64
      int ob = i * 4096 + wub;
      int o_ = ob + (lane << 4);
      int r = o_ >> 7, cb = o_ & 127;
      int cbs = cb ^ ((r & 7) << 4);
      stage16((const char*)(Vt + head) + (long)r * (SS * 2) + kvbase * 2 + cbs, (char*)Vts + ob);
    }
    __syncthreads();

    // S = Q K^T (per wave: 16 q-rows x 64 kv)
    f32x4 sf[4];
    #pragma unroll
    for (int nf = 0; nf < 4; ++nf) {
      f32x4 s = {0.f, 0.f, 0.f, 0.f};
      #pragma unroll
      for (int kc = 0; kc < 4; ++kc) {
        int r = nf * 16 + c;
        int ab = (r << 8) + kc * 64 + (g << 4);
        ab ^= (r & 7) << 4;
        bf16x8 kf = *(const bf16x8*)((const char*)Ks + ab);
        s = __builtin_amdgcn_mfma_f32_16x16x32_bf16(qf[kc], kf, s, 0, 0, 0);
      }
      sf[nf] = s;
    }

    if (t == qt) {  // diagonal tile: strict causal mask
      #pragma unroll
      for (int nf = 0; nf < 4; ++nf)
        #pragma unroll
        for (int j = 0; j < 4; ++j)
          if (nf * 16 + c > w * 16 + g * 4 + j) sf[nf][j] = -INFINITY;
    }

    // online softmax (rows live on 16-lane groups, reduce over lane&15)
    float mn[4], cf[4], rs[4];
    #pragma unroll
    for (int j = 0; j < 4; ++j) {
      float v = fmaxf(fmaxf(sf[0][j], sf[1][j]), fmaxf(sf[2][j], sf[3][j]));
      v = fmaxf(v, __shfl_xor(v, 1));
      v = fmaxf(v, __shfl_xor(v, 2));
      v = fmaxf(v, __shfl_xor(v, 4));
      v = fmaxf(v, __shfl_xor(v, 8));
      mn[j] = fmaxf(m[j], v);
      cf[j] = exp2f((m[j] - mn[j]) * 1.4426950408889634f);
      m[j] = mn[j];
      rs[j] = 0.f;
    }
    #pragma unroll
    for (int nf = 0; nf < 4; ++nf)
      #pragma unroll
      for (int j = 0; j < 4; ++j) {
        float p = exp2f((sf[nf][j] - mn[j]) * 1.4426950408889634f);
        sf[nf][j] = p;
        rs[j] += p;
      }
    #pragma unroll
    for (int j = 0; j < 4; ++j) {
      float v = rs[j];
      v += __shfl_xor(v, 1); v += __shfl_xor(v, 2);
      v += __shfl_xor(v, 4); v += __shfl_xor(v, 8);
      l[j] = l[j] * cf[j] + v;
    }
    #pragma unroll
    for (int nf = 0; nf < 8; ++nf)
      #pragma unroll
      for (int j = 0; j < 4; ++j)
        o[nf][j] *= cf[j];

    // P -> wave-private LDS (C-layout -> A-layout redistribution)
    #pragma unroll
    for (int nf = 0; nf < 4; ++nf)
      #pragma unroll
      for (int j = 0; j < 4; ++j) {
        int pr = g * 4 + j;
        int ab = (pr << 7) + (nf * 16 + c) * 2;
        ab ^= (pr & 7) << 4;
        *(u16*)((char*)Ps[w] + ab) = f2bf(sf[nf][j]);
      }

    // O += P V
    bf16x8 pf[2];
    #pragma unroll
    for (int kc = 0; kc < 2; ++kc) {
      int ab = (c << 7) + kc * 64 + (g << 4);
      ab ^= (c & 7) << 4;
      pf[kc] = *(const bf16x8*)((const char*)Ps[w] + ab);
    }
    #pragma unroll
    for (int nf = 0; nf < 8; ++nf) {
      #pragma unroll
      for (int kc = 0; kc < 2; ++kc) {
        int r = nf * 16 + c;
        int ab = (r << 7) + kc * 64 + (g << 4);
        ab ^= (r & 7) << 4;
        bf16x8 vf = *(const bf16x8*)((const char*)Vts + ab);
        o[nf] = __builtin_amdgcn_mfma_f32_16x16x32_bf16(pf[kc], vf, o[nf], 0, 0, 0);
      }
    }
    __syncthreads();
  }

  #pragma unroll
  for (int j = 0; j < 4; ++j) {
    float inv = 1.0f / l[j];
    int row = qbase + w * 16 + g * 4 + j;
    long ob = ((long)(b * SS + row)) * DMM + h * DHH;
    #pragma unroll
    for (int nf = 0; nf < 8; ++nf)
      Ao[ob + nf * 16 + c] = f2bf(o[nf][j] * inv);
  }
}

extern "C" void kernel_launch(void* const* d_in, const int* in_sizes, int n_in,
                              void* d_out, int out_size, void* d_ws, size_t ws_size,
                              hipStream_t stream) {
  const float* x     = (const float*)d_in[0];
  const float* w_qkv = (const float*)d_in[1];
  const float* b_qkv = (const float*)d_in[2];
  const float* w_out = (const float*)d_in[3];
  const float* b_out = (const float*)d_in[4];
  const float* fcr   = (const float*)d_in[5];
  const float* fci   = (const float*)d_in[6];
  // d_in[7] mask: causal triu(k=1), hardcoded in attn_k
  float* outp = (float*)d_out;

  char* ws = (char*)d_ws;               // needs 96 MB
  u16* xb  = (u16*)(ws + 0);            // 16MB x bf16 [4096][2048]
  u16* wqb = (u16*)(ws + (16L << 20));  // 24MB w_qkv bf16 [6144][2048]
  u16* wob = (u16*)(ws + (40L << 20));  // 8MB  w_out bf16 [2048][2048]
  u16* Qb  = (u16*)(ws + (48L << 20));  // 16MB [bh][s][128] (scaled+roped)
  u16* Kb  = (u16*)(ws + (64L << 20));  // 16MB [bh][s][128] (roped)
  u16* Vtb = (u16*)(ws + (80L << 20));  // 16MB [bh][128][s]
  u16* attno = xb;                      // alias: xb dead after GEMM1

  cvt_bf16_k<<<4096, 256, 0, stream>>>(x, xb);
  cvt_bf16_k<<<6144, 256, 0, stream>>>(w_qkv, wqb);
  cvt_bf16_k<<<2048, 256, 0, stream>>>(w_out, wob);

  gemm_bt_k<0><<<dim3(48, 32), 256, 0, stream>>>(
      xb, wqb, b_qkv, fcr, fci, Qb, Kb, Vtb, nullptr, 4096, 6144, 2048);

  attn_k<<<dim3(32, 32), 256, 0, stream>>>(Qb, Kb, Vtb, attno);

  gemm_bt_k<1><<<dim3(16, 32), 256, 0, stream>>>(
      attno, wob, b_out, nullptr, nullptr, nullptr, nullptr, nullptr, outp,
      4096, 2048, 2048);
}